// Round 1
// baseline (161.110 us; speedup 1.0000x reference)
//
#include <hip/hip_runtime.h>
#include <hip/hip_bf16.h>
#include <stdint.h>

#define B_    32
#define CIN   128
#define COUT  128
#define KEXP  4
#define HW_   12544   // 112*112

typedef __attribute__((ext_vector_type(8))) short bf16x8;
typedef __attribute__((ext_vector_type(4))) float f32x4;

// fp32 -> bf16 round-to-nearest-even (no NaN handling needed: inputs are finite)
static __device__ __forceinline__ short f2bf(float f) {
    uint32_t u = __builtin_bit_cast(uint32_t, f);
    u += 0x7FFFu + ((u >> 16) & 1u);
    return (short)(u >> 16);
}

// ---------------------------------------------------------------------------
// Kernel 1: pooled[b][i] = mean_{hw} x[b][i][hw].  One block per (b,i) row.
// ---------------------------------------------------------------------------
__global__ __launch_bounds__(256) void pool_kernel(const float* __restrict__ x,
                                                   float* __restrict__ pooled) {
    const int row = blockIdx.x;                 // b*128 + i
    const float4* __restrict__ x4 = (const float4*)(x + (size_t)row * HW_);
    const int t = threadIdx.x;
    float s = 0.f;
    for (int idx = t; idx < HW_ / 4; idx += 256) {   // 3136 float4
        float4 v = x4[idx];
        s += (v.x + v.y) + (v.z + v.w);
    }
    #pragma unroll
    for (int off = 32; off > 0; off >>= 1) s += __shfl_down(s, off, 64);
    __shared__ float wsum[4];
    if ((t & 63) == 0) wsum[t >> 6] = s;
    __syncthreads();
    if (t == 0) pooled[row] = (wsum[0] + wsum[1] + wsum[2] + wsum[3]) * (1.0f / HW_);
}

// ---------------------------------------------------------------------------
// Kernel 2: gate (softmax over K=4) + combine expert weights -> bf16 w_mix.
// One block per batch sample.
// ---------------------------------------------------------------------------
__global__ __launch_bounds__(256) void gate_kernel(const float* __restrict__ pooled,
                                                   const float* __restrict__ gate_w,
                                                   const float* __restrict__ gate_b,
                                                   const float* __restrict__ expert_w,
                                                   short* __restrict__ wmix) {
    const int b = blockIdx.x;
    const int t = threadIdx.x;
    const int wid = t >> 6, lane = t & 63;
    __shared__ float logits[KEXP];
    __shared__ float gsh[KEXP];
    // wave wid computes logit for expert wid (KEXP==4 waves)
    {
        float p0 = pooled[b * CIN + lane];
        float p1 = pooled[b * CIN + 64 + lane];
        float s = p0 * gate_w[wid * CIN + lane] + p1 * gate_w[wid * CIN + 64 + lane];
        #pragma unroll
        for (int off = 32; off > 0; off >>= 1) s += __shfl_down(s, off, 64);
        if (lane == 0) logits[wid] = s + gate_b[wid];
    }
    __syncthreads();
    if (t == 0) {
        float m = fmaxf(fmaxf(logits[0], logits[1]), fmaxf(logits[2], logits[3]));
        float e0 = expf(logits[0] - m), e1 = expf(logits[1] - m);
        float e2 = expf(logits[2] - m), e3 = expf(logits[3] - m);
        float inv = 1.f / (e0 + e1 + e2 + e3);
        gsh[0] = e0 * inv; gsh[1] = e1 * inv; gsh[2] = e2 * inv; gsh[3] = e3 * inv;
    }
    __syncthreads();
    const float g0 = gsh[0], g1 = gsh[1], g2 = gsh[2], g3 = gsh[3];
    for (int idx = t; idx < COUT * CIN; idx += 256) {
        float w = g0 * expert_w[idx]
                + g1 * expert_w[COUT * CIN + idx]
                + g2 * expert_w[2 * COUT * CIN + idx]
                + g3 * expert_w[3 * COUT * CIN + idx];
        wmix[b * COUT * CIN + idx] = f2bf(w);
    }
}

// ---------------------------------------------------------------------------
// Kernel 3: out[b] = w_mix[b] (128x128) @ x[b] (128x12544), bf16 MFMA.
// Block = 256 thr = 4 waves; block covers 64 pixels, wave owns 16 pixels x
// all 128 Cout. W in LDS (XOR-swizzled, G4); X global->reg (no reuse).
// ---------------------------------------------------------------------------
__global__ __launch_bounds__(256) void conv_kernel(const float* __restrict__ x,
                                                   const short* __restrict__ wmix,
                                                   float* __restrict__ out) {
    __shared__ char wlds[COUT * 256];           // 128 rows x 256B (bf16), swizzled
    const int b  = blockIdx.y;
    const int p0 = blockIdx.x * 64;
    const int t  = threadIdx.x;

    // ---- stage W (bf16) into LDS with XOR swizzle: byte ^= (row&7)<<4 ----
    {
        const uint4* __restrict__ wsrc = (const uint4*)(wmix + (size_t)b * COUT * CIN);
        #pragma unroll
        for (int pass = 0; pass < 8; ++pass) {
            int o  = (t >> 4) + pass * 16;      // row (Cout)
            int i4 = t & 15;                    // 16B unit within row
            uint4 v = wsrc[o * 16 + i4];
            int byte = (o * 256 + i4 * 16) ^ ((o & 7) << 4);
            *(uint4*)(wlds + byte) = v;
        }
    }

    const int wave = t >> 6;
    const int lane = t & 63;
    const int n = lane & 15;                    // pixel within 16-group (MFMA N)
    const int h = lane >> 4;                    // k-chunk-of-8 selector
    const int pix = p0 + wave * 16 + n;

    // ---- load this wave's X column slice: 32 fp32 per lane (all 128 cin) ----
    const float* __restrict__ xb = x + (size_t)b * CIN * HW_ + pix;
    float xv[32];
    #pragma unroll
    for (int kk = 0; kk < 4; ++kk)
        #pragma unroll
        for (int j = 0; j < 8; ++j)
            xv[kk * 8 + j] = xb[(size_t)(kk * 32 + h * 8 + j) * HW_];

    bf16x8 bfrag[4];
    #pragma unroll
    for (int kk = 0; kk < 4; ++kk)
        #pragma unroll
        for (int j = 0; j < 8; ++j)
            bfrag[kk][j] = f2bf(xv[kk * 8 + j]);

    __syncthreads();

    f32x4 acc[8];
    #pragma unroll
    for (int ot = 0; ot < 8; ++ot) acc[ot] = (f32x4){0.f, 0.f, 0.f, 0.f};

    // ---- K-loop: 4 chunks of 32 cin; 8 Cout tiles of 16 ----
    #pragma unroll
    for (int kk = 0; kk < 4; ++kk) {
        #pragma unroll
        for (int ot = 0; ot < 8; ++ot) {
            int o = ot * 16 + n;                // A row = Cout (lane&15)
            int byte = (o * 256 + kk * 64 + h * 16) ^ ((o & 7) << 4);
            bf16x8 afrag = *(const bf16x8*)(wlds + byte);
            acc[ot] = __builtin_amdgcn_mfma_f32_16x16x32_bf16(afrag, bfrag[kk], acc[ot], 0, 0, 0);
        }
    }

    // ---- epilogue: C/D layout col=lane&15 (pixel), row=(lane>>4)*4+r (Cout) ----
    float* __restrict__ ob = out + (size_t)b * COUT * HW_ + pix;
    #pragma unroll
    for (int ot = 0; ot < 8; ++ot)
        #pragma unroll
        for (int r = 0; r < 4; ++r)
            ob[(size_t)(ot * 16 + h * 4 + r) * HW_] = acc[ot][r];
}

// ---------------------------------------------------------------------------
extern "C" void kernel_launch(void* const* d_in, const int* in_sizes, int n_in,
                              void* d_out, int out_size, void* d_ws, size_t ws_size,
                              hipStream_t stream) {
    const float* x        = (const float*)d_in[0];
    const float* expert_w = (const float*)d_in[1];
    const float* gate_w   = (const float*)d_in[2];
    const float* gate_b   = (const float*)d_in[3];
    float* out = (float*)d_out;

    float* pooled = (float*)d_ws;                          // 32*128 fp32 = 16 KB
    short* wmix   = (short*)((char*)d_ws + 16384);         // 32*128*128 bf16 = 1 MB

    pool_kernel<<<dim3(B_ * CIN), 256, 0, stream>>>(x, pooled);
    gate_kernel<<<dim3(B_), 256, 0, stream>>>(pooled, gate_w, gate_b, expert_w, wmix);
    conv_kernel<<<dim3(HW_ / 64, B_), 256, 0, stream>>>(x, wmix, out);
}

// Round 2
// 131.831 us; speedup vs baseline: 1.2221x; 1.2221x over previous
//
#include <hip/hip_runtime.h>
#include <hip/hip_bf16.h>
#include <stdint.h>

#define B_    32
#define CIN   128
#define COUT  128
#define KEXP  4
#define HW_   12544   // 112*112

typedef __attribute__((ext_vector_type(8))) short bf16x8;
typedef __attribute__((ext_vector_type(4))) float f32x4;

// fp32 -> bf16 round-to-nearest-even (inputs finite, no NaN handling)
static __device__ __forceinline__ ushort f2bf(float f) {
    uint32_t u = __builtin_bit_cast(uint32_t, f);
    u += 0x7FFFu + ((u >> 16) & 1u);
    return (ushort)(u >> 16);
}

// ---------------------------------------------------------------------------
// Kernel 1: pooled[b][i] = mean_{hw} x[b][i][hw].  One block per (b,i) row.
// Normal (caching) loads on purpose: this pass warms the 256MB L3 with x so
// conv_kernel's second read of x hits L3.
// ---------------------------------------------------------------------------
__global__ __launch_bounds__(256) void pool_kernel(const float* __restrict__ x,
                                                   float* __restrict__ pooled) {
    const int row = blockIdx.x;                 // b*128 + i
    const float4* __restrict__ x4 = (const float4*)(x + (size_t)row * HW_);
    const int t = threadIdx.x;
    float s = 0.f;
    for (int idx = t; idx < HW_ / 4; idx += 256) {   // 3136 float4
        float4 v = x4[idx];
        s += (v.x + v.y) + (v.z + v.w);
    }
    #pragma unroll
    for (int off = 32; off > 0; off >>= 1) s += __shfl_down(s, off, 64);
    __shared__ float wsum[4];
    if ((t & 63) == 0) wsum[t >> 6] = s;
    __syncthreads();
    if (t == 0) pooled[row] = (wsum[0] + wsum[1] + wsum[2] + wsum[3]) * (1.0f / HW_);
}

// ---------------------------------------------------------------------------
// Kernel 2: gate (softmax over K=4) + combine expert weights -> bf16 w_mix.
// One block per batch sample.
// ---------------------------------------------------------------------------
__global__ __launch_bounds__(256) void gate_kernel(const float* __restrict__ pooled,
                                                   const float* __restrict__ gate_w,
                                                   const float* __restrict__ gate_b,
                                                   const float* __restrict__ expert_w,
                                                   short* __restrict__ wmix) {
    const int b = blockIdx.x;
    const int t = threadIdx.x;
    const int wid = t >> 6, lane = t & 63;
    __shared__ float logits[KEXP];
    __shared__ float gsh[KEXP];
    {
        float p0 = pooled[b * CIN + lane];
        float p1 = pooled[b * CIN + 64 + lane];
        float s = p0 * gate_w[wid * CIN + lane] + p1 * gate_w[wid * CIN + 64 + lane];
        #pragma unroll
        for (int off = 32; off > 0; off >>= 1) s += __shfl_down(s, off, 64);
        if (lane == 0) logits[wid] = s + gate_b[wid];
    }
    __syncthreads();
    if (t == 0) {
        float m = fmaxf(fmaxf(logits[0], logits[1]), fmaxf(logits[2], logits[3]));
        float e0 = expf(logits[0] - m), e1 = expf(logits[1] - m);
        float e2 = expf(logits[2] - m), e3 = expf(logits[3] - m);
        float inv = 1.f / (e0 + e1 + e2 + e3);
        gsh[0] = e0 * inv; gsh[1] = e1 * inv; gsh[2] = e2 * inv; gsh[3] = e3 * inv;
    }
    __syncthreads();
    const float g0 = gsh[0], g1 = gsh[1], g2 = gsh[2], g3 = gsh[3];
    for (int idx = t; idx < COUT * CIN; idx += 256) {
        float w = g0 * expert_w[idx]
                + g1 * expert_w[COUT * CIN + idx]
                + g2 * expert_w[2 * COUT * CIN + idx]
                + g3 * expert_w[3 * COUT * CIN + idx];
        wmix[b * COUT * CIN + idx] = (short)f2bf(w);
    }
}

// ---------------------------------------------------------------------------
// Kernel 3: out[b] = w_mix[b] (128x128) @ x[b] (128x12544), bf16 MFMA.
// Block = 4 waves, 64 pixels. A = X-tile (M=pix), B = W (N=cout) so the C/D
// layout (col=lane&15, row=(lane>>4)*4+r) gives float4 pixel-contiguous
// stores. X staged float4 -> reg-transpose -> bf16 LDS (XOR-swizzled);
// W staged bf16 LDS (XOR-swizzled). out written nontemporal (keep x in L3).
// ---------------------------------------------------------------------------
__global__ __launch_bounds__(256) void conv_kernel(const float* __restrict__ x,
                                                   const short* __restrict__ wmix,
                                                   float* __restrict__ out) {
    __shared__ char wlds[COUT * 256];           // 128 rows (cout) x 256B, swizzled
    __shared__ char xlds[64 * 256];             // 64 rows (pix) x 256B (128 cin bf16), swizzled
    const int b  = blockIdx.y;
    const int p0 = blockIdx.x * 64;
    const int t  = threadIdx.x;

    // ---- stage W (bf16) into LDS, swizzle byte ^= (row&7)<<4 ----
    {
        const uint4* __restrict__ wsrc = (const uint4*)(wmix + (size_t)b * COUT * CIN);
        #pragma unroll
        for (int pass = 0; pass < 8; ++pass) {
            int o  = (t >> 4) + pass * 16;      // cout row
            int i4 = t & 15;                    // 16B unit within row
            uint4 v = wsrc[o * 16 + i4];
            int byte = (o * 256 + i4 * 16) ^ ((o & 7) << 4);
            *(uint4*)(wlds + byte) = v;
        }
    }

    // ---- stage X tile [128 cin][64 pix] -> xlds[pix][cin] bf16, swizzled ----
    {
        const int pg = t & 15;                  // pixel 4-group
        const int cg = t >> 4;                  // cin 4-group within pass
        #pragma unroll
        for (int p = 0; p < 2; ++p) {
            const int cin0 = p * 64 + cg * 4;
            const float* xrow = x + (size_t)b * CIN * HW_ + (size_t)cin0 * HW_ + p0 + pg * 4;
            float va[4][4];
            #pragma unroll
            for (int i = 0; i < 4; ++i) {
                float4 v = *(const float4*)(xrow + (size_t)i * HW_);
                va[i][0] = v.x; va[i][1] = v.y; va[i][2] = v.z; va[i][3] = v.w;
            }
            #pragma unroll
            for (int j = 0; j < 4; ++j) {
                const int pix = pg * 4 + j;
                uint32_t lo = (uint32_t)f2bf(va[0][j]) | ((uint32_t)f2bf(va[1][j]) << 16);
                uint32_t hi = (uint32_t)f2bf(va[2][j]) | ((uint32_t)f2bf(va[3][j]) << 16);
                int byte = (pix * 256 + cin0 * 2) ^ ((pix & 7) << 4);
                uint2 w2; w2.x = lo; w2.y = hi;
                *(uint2*)(xlds + byte) = w2;
            }
        }
    }

    const int wave = t >> 6;
    const int lane = t & 63;
    const int n = lane & 15;                    // MFMA row/col within 16
    const int h = lane >> 4;                    // k-octet selector

    __syncthreads();

    // ---- A fragments: this lane's pixel row, 4 k-chunks (hoisted) ----
    bf16x8 xfrag[4];
    {
        const int pixl = wave * 16 + n;
        #pragma unroll
        for (int kk = 0; kk < 4; ++kk) {
            int byte = (pixl * 256 + kk * 64 + h * 16) ^ ((pixl & 7) << 4);
            xfrag[kk] = *(const bf16x8*)(xlds + byte);
        }
    }

    f32x4 acc[8];
    #pragma unroll
    for (int ot = 0; ot < 8; ++ot) acc[ot] = (f32x4){0.f, 0.f, 0.f, 0.f};

    // ---- K-loop: 4 chunks of 32 cin; 8 cout tiles of 16 ----
    #pragma unroll
    for (int kk = 0; kk < 4; ++kk) {
        #pragma unroll
        for (int ot = 0; ot < 8; ++ot) {
            int o = ot * 16 + n;                // B col = cout
            int byte = (o * 256 + kk * 64 + h * 16) ^ ((o & 7) << 4);
            bf16x8 wfrag = *(const bf16x8*)(wlds + byte);
            acc[ot] = __builtin_amdgcn_mfma_f32_16x16x32_bf16(xfrag[kk], wfrag, acc[ot], 0, 0, 0);
        }
    }

    // ---- epilogue: col(lane&15)=cout, row=(lane>>4)*4+r = pixel -> float4 nt store ----
    float* __restrict__ ob = out + (size_t)b * COUT * HW_ + p0 + wave * 16 + h * 4;
    #pragma unroll
    for (int ot = 0; ot < 8; ++ot) {
        int cout = ot * 16 + n;
        __builtin_nontemporal_store(acc[ot], (f32x4*)(ob + (size_t)cout * HW_));
    }
}

// ---------------------------------------------------------------------------
extern "C" void kernel_launch(void* const* d_in, const int* in_sizes, int n_in,
                              void* d_out, int out_size, void* d_ws, size_t ws_size,
                              hipStream_t stream) {
    const float* x        = (const float*)d_in[0];
    const float* expert_w = (const float*)d_in[1];
    const float* gate_w   = (const float*)d_in[2];
    const float* gate_b   = (const float*)d_in[3];
    float* out = (float*)d_out;

    float* pooled = (float*)d_ws;                          // 32*128 fp32 = 16 KB
    short* wmix   = (short*)((char*)d_ws + 16384);         // 32*128*128 bf16 = 1 MB

    pool_kernel<<<dim3(B_ * CIN), 256, 0, stream>>>(x, pooled);
    gate_kernel<<<dim3(B_), 256, 0, stream>>>(pooled, gate_w, gate_b, expert_w, wmix);
    conv_kernel<<<dim3(HW_ / 64, B_), 256, 0, stream>>>(x, wmix, out);
}